// Round 13
// baseline (57.674 us; speedup 1.0000x reference)
//
#include <hip/hip_runtime.h>
#include <hip/hip_bf16.h>

// out[b,t,u,c] = enc[b,t,:]·W[c,:512] + dec[b,u,:]·W[c,512:]
// B=4, T=256, U=64, D=512, C=1024. Output 256 MiB fp32 (write floor ~39us).
//
// K1 (merged): blocks [0,512) = fp32->bf16 fragment permute of enc + Wenc;
//              blocks [512,768) = dec projection GEMM with INLINE cvt loads
//              (R2-proven), no dependency on the cvt blocks -> one dispatch.
// K2 fused:    per block (16 bt x 64 c): enc MFMA tile (frag loads) -> LDS,
//              barrier, stream 256 KiB; Pd read per-u directly from L2
//              (wave-broadcast), plain cached float4 stores (R12 lesson:
//              nontemporal stores throttle streaming writes ~22%).

typedef float v4f   __attribute__((ext_vector_type(4)));
typedef float f32x4 __attribute__((ext_vector_type(4)));
typedef __attribute__((ext_vector_type(8))) short short8;

__device__ inline short bf16_of(float f) {
    __hip_bfloat16 h = __float2bfloat16(f);   // RNE
    return *reinterpret_cast<short*>(&h);
}

__device__ inline short8 load_cvt_bf16x8(const float* __restrict__ p) {
    float4 lo = *(const float4*)p;
    float4 hi = *(const float4*)(p + 4);
    short8 r;
    r[0] = bf16_of(lo.x); r[1] = bf16_of(lo.y); r[2] = bf16_of(lo.z); r[3] = bf16_of(lo.w);
    r[4] = bf16_of(hi.x); r[5] = bf16_of(hi.y); r[6] = bf16_of(hi.z); r[7] = bf16_of(hi.w);
    return r;
}

// ---------------- K1: cvt(enc,Wenc) + dec projection GEMM -------------------
// Grid 768 blocks x 256 threads.
//  blocks [0,512): wave-task gid = blk*4+w in [0,2048):
//    [0,1024)    enc  frag blocks (64 mb x 16 kb) -> Xe_f
//    [1024,2048) Wenc frag blocks (64 cb x 16 kb) -> We_f
//  blocks [512,768): dec tile task = blk-512: mb = task>>4, cb4 = task&15;
//    16(m) x 64(c) tile, 2-way split-K, inline-cvt scattered loads.
__global__ __launch_bounds__(256) void cvt_and_dec(
    const float* __restrict__ enc,   // (1024, 512)
    const float* __restrict__ dec,   // (256, 512)
    const float* __restrict__ W,     // (1024, 1024)
    ushort* __restrict__ Xe_f, ushort* __restrict__ We_f,
    float* __restrict__ Pd)          // (256, 1024)
{
    const int tid  = threadIdx.x;
    const int w    = tid >> 6;
    const int lane = tid & 63;
    const int l16  = lane & 15;
    const int kq   = lane >> 4;

    if (blockIdx.x < 512) {
        // ---- cvt + fragment permute ----
        const int gid = blockIdx.x * 4 + w;
        const float* src; ushort* dst; int g, rs;
        if (gid < 1024) { src = enc; dst = Xe_f; g = gid;        rs = 512;  }
        else            { src = W;   dst = We_f; g = gid - 1024; rs = 1024; }
        const int rb = g >> 4, kbi = g & 15;
        const float* p = src + (size_t)(rb * 16 + l16) * rs + kbi * 32 + kq * 8;
        short8 o = load_cvt_bf16x8(p);
        *(short8*)&dst[(size_t)g * 512 + lane * 8] = o;
        return;
    }

    // ---- dec projection GEMM tile (inline cvt, split-K) ----
    const int task  = blockIdx.x - 512;       // 0..255
    const int mb    = task >> 4;
    const int cb4   = task & 15;
    const int kz    = w >> 1;                 // K half: [kz*256, kz*256+256)
    const int wn    = (w & 1) * 32;
    const int cBase = cb4 * 64;

    const float* xr  = dec + (size_t)(mb * 16 + l16) * 512 + kz * 256;
    const float* wr0 = W + (size_t)(cBase + wn + l16) * 1024 + 512 + kz * 256;
    const float* wr1 = wr0 + (size_t)16 * 1024;

    f32x4 a0 = {0.f,0.f,0.f,0.f}, a1 = {0.f,0.f,0.f,0.f};
#pragma unroll 4
    for (int kb = 0; kb < 256; kb += 32) {
        const int k = kb + kq * 8;
        short8 a  = load_cvt_bf16x8(xr + k);
        short8 b0 = load_cvt_bf16x8(wr0 + k);
        short8 b1 = load_cvt_bf16x8(wr1 + k);
        a0 = __builtin_amdgcn_mfma_f32_16x16x32_bf16(a, b0, a0, 0, 0, 0);
        a1 = __builtin_amdgcn_mfma_f32_16x16x32_bf16(a, b1, a1, 0, 0, 0);
    }

    __shared__ float Ps[16][65];
    if (kz == 1) {
#pragma unroll
        for (int r = 0; r < 4; ++r) {
            Ps[kq * 4 + r][wn + l16]      = a0[r];
            Ps[kq * 4 + r][wn + 16 + l16] = a1[r];
        }
    }
    __syncthreads();
    if (kz == 0) {
        float* p0 = Pd + (size_t)(mb * 16) * 1024 + cBase + wn;
#pragma unroll
        for (int r = 0; r < 4; ++r) {
            const int row = kq * 4 + r;
            p0[(size_t)row * 1024 + l16]      = a0[r] + Ps[row][wn + l16];
            p0[(size_t)row * 1024 + 16 + l16] = a1[r] + Ps[row][wn + 16 + l16];
        }
    }
}

// ---------------- K2: fused enc GEMM + broadcast-add stream ------------------
// Grid (16 c-tiles, 64 bt-tiles), 256 threads = 4 waves.
__global__ __launch_bounds__(256) void fused_enc_stream(
    const ushort* __restrict__ Xe_f,  // frag layout (64 mb x 16 kb)
    const ushort* __restrict__ We_f,  // frag layout (64 cb x 16 kb)
    const float* __restrict__ Pd,     // (256, 1024)
    float* __restrict__ out)          // (1024, 64, 1024)
{
    const int tid  = threadIdx.x;
    const int wave = tid >> 6;
    const int lane = tid & 63;
    const int l16  = lane & 15;
    const int kq   = lane >> 4;

    const int kz = wave >> 1;
    const int wn = (wave & 1) * 32;
    const int btBase = blockIdx.y * 16;
    const int cBase  = blockIdx.x * 64;
    const int b      = blockIdx.y >> 4;
    const int cb0    = blockIdx.x * 4 + (wave & 1) * 2;

    __shared__ float encS[2][16][68];

    // Enc GEMM: 16 x 64 tile, fragment loads, 2-way split-K.
    {
        const short8* xa  = (const short8*)Xe_f + (size_t)(blockIdx.y * 16 + kz * 8) * 64 + lane;
        const short8* wb0 = (const short8*)We_f + (size_t)(cb0       * 16 + kz * 8) * 64 + lane;
        const short8* wb1 = (const short8*)We_f + (size_t)((cb0 + 1) * 16 + kz * 8) * 64 + lane;
        f32x4 a0 = {0.f,0.f,0.f,0.f}, a1 = {0.f,0.f,0.f,0.f};
#pragma unroll
        for (int s = 0; s < 8; ++s) {
            short8 a  = xa [(size_t)s * 64];
            short8 b0 = wb0[(size_t)s * 64];
            short8 b1 = wb1[(size_t)s * 64];
            a0 = __builtin_amdgcn_mfma_f32_16x16x32_bf16(a, b0, a0, 0, 0, 0);
            a1 = __builtin_amdgcn_mfma_f32_16x16x32_bf16(a, b1, a1, 0, 0, 0);
        }
#pragma unroll
        for (int r = 0; r < 4; ++r) {        // D: col=l16, row=kq*4+r
            encS[kz][kq * 4 + r][wn + l16]      = a0[r];
            encS[kz][kq * 4 + r][wn + 16 + l16] = a1[r];
        }
    }

    __syncthreads();

    // Stream: thread (row=tid>>4, slot=tid&15); Pd read per u from L2
    // (16 distinct float4 per block per u -> wave broadcast), cached stores.
    const int row = tid >> 4;
    const int c4  = (tid & 15) * 4;

    const float4 e0 = *(const float4*)&encS[0][row][c4];
    const float4 e1 = *(const float4*)&encS[1][row][c4];
    const v4f e = {e0.x + e1.x, e0.y + e1.y, e0.z + e1.z, e0.w + e1.w};

    const float* pd = Pd + (size_t)(b * 64) * 1024 + cBase + c4;
    float*       po = out + (size_t)(btBase + row) * 64 * 1024 + cBase + c4;

#pragma unroll 8
    for (int u = 0; u < 64; ++u) {
        float4 d = *(const float4*)&pd[(size_t)u * 1024];
        v4f r = {e.x + d.x, e.y + d.y, e.z + d.z, e.w + d.w};
        *(v4f*)&po[(size_t)u * 1024] = r;
    }
}

extern "C" void kernel_launch(void* const* d_in, const int* in_sizes, int n_in,
                              void* d_out, int out_size, void* d_ws, size_t ws_size,
                              hipStream_t stream) {
    const float* enc = (const float*)d_in[0];   // (4,256,512)
    const float* dec = (const float*)d_in[1];   // (4,64,512)
    const float* W   = (const float*)d_in[2];   // (1024,1024)
    float* out = (float*)d_out;

    // Workspace: Pd 1 MiB | Xe_f 1 MiB | We_f 1 MiB   (= 3 MiB)
    char* ws = (char*)d_ws;
    float*  Pd   = (float*)(ws);
    ushort* Xe_f = (ushort*)(ws + (1u << 20));
    ushort* We_f = (ushort*)(ws + (2u << 20));

    cvt_and_dec<<<dim3(768), 256, 0, stream>>>(enc, dec, W, Xe_f, We_f, Pd);
    fused_enc_stream<<<dim3(16, 64), 256, 0, stream>>>(Xe_f, We_f, Pd, out);
}

// Round 14
// 57.139 us; speedup vs baseline: 1.0094x; 1.0094x over previous
//
#include <hip/hip_runtime.h>
#include <hip/hip_bf16.h>

// out[b,t,u,c] = enc[b,t,:]·W[c,:512] + dec[b,u,:]·W[c,512:]
// B=4, T=256, U=64, D=512, C=1024. Output 256 MiB fp32 (write floor ~39us).
//
// K1 (merged): blocks [0,512) = fp32->bf16 fragment permute of enc + Wenc;
//              blocks [512,768) = dec projection GEMM with inline-cvt loads
//              (independent of the cvt blocks -> one dispatch, one drain).
// K2 fused:    per block (16 bt x 64 c): Pd chunk -> decS (LDS, R12-proven),
//              enc MFMA tile (frag loads) -> encS, barrier, stream 256 KiB
//              with plain cached float4 stores (R12 lesson: NT stores
//              throttle streaming writes ~22%).

typedef float v4f   __attribute__((ext_vector_type(4)));
typedef float f32x4 __attribute__((ext_vector_type(4)));
typedef __attribute__((ext_vector_type(8))) short short8;

__device__ inline short bf16_of(float f) {
    __hip_bfloat16 h = __float2bfloat16(f);   // RNE
    return *reinterpret_cast<short*>(&h);
}

__device__ inline short8 load_cvt_bf16x8(const float* __restrict__ p) {
    float4 lo = *(const float4*)p;
    float4 hi = *(const float4*)(p + 4);
    short8 r;
    r[0] = bf16_of(lo.x); r[1] = bf16_of(lo.y); r[2] = bf16_of(lo.z); r[3] = bf16_of(lo.w);
    r[4] = bf16_of(hi.x); r[5] = bf16_of(hi.y); r[6] = bf16_of(hi.z); r[7] = bf16_of(hi.w);
    return r;
}

// ---------------- K1: cvt(enc,Wenc) + dec projection GEMM -------------------
// Grid 768 blocks x 256 threads.
//  blocks [0,512): wave-task gid = blk*4+w in [0,2048):
//    [0,1024)    enc  frag blocks (64 mb x 16 kb) -> Xe_f
//    [1024,2048) Wenc frag blocks (64 cb x 16 kb) -> We_f
//  blocks [512,768): dec tile task: mb = task>>4, cb4 = task&15;
//    16(m) x 64(c) tile, 2-way split-K, inline-cvt loads.
__global__ __launch_bounds__(256) void cvt_and_dec(
    const float* __restrict__ enc,   // (1024, 512)
    const float* __restrict__ dec,   // (256, 512)
    const float* __restrict__ W,     // (1024, 1024)
    ushort* __restrict__ Xe_f, ushort* __restrict__ We_f,
    float* __restrict__ Pd)          // (256, 1024)
{
    const int tid  = threadIdx.x;
    const int w    = tid >> 6;
    const int lane = tid & 63;
    const int l16  = lane & 15;
    const int kq   = lane >> 4;

    if (blockIdx.x < 512) {
        // ---- cvt + fragment permute ----
        const int gid = blockIdx.x * 4 + w;
        const float* src; ushort* dst; int g, rs;
        if (gid < 1024) { src = enc; dst = Xe_f; g = gid;        rs = 512;  }
        else            { src = W;   dst = We_f; g = gid - 1024; rs = 1024; }
        const int rb = g >> 4, kbi = g & 15;
        const float* p = src + (size_t)(rb * 16 + l16) * rs + kbi * 32 + kq * 8;
        short8 o = load_cvt_bf16x8(p);
        *(short8*)&dst[(size_t)g * 512 + lane * 8] = o;
        return;
    }

    // ---- dec projection GEMM tile (inline cvt, split-K) ----
    const int task  = blockIdx.x - 512;       // 0..255
    const int mb    = task >> 4;
    const int cb4   = task & 15;
    const int kz    = w >> 1;                 // K half: [kz*256, kz*256+256)
    const int wn    = (w & 1) * 32;
    const int cBase = cb4 * 64;

    const float* xr  = dec + (size_t)(mb * 16 + l16) * 512 + kz * 256;
    const float* wr0 = W + (size_t)(cBase + wn + l16) * 1024 + 512 + kz * 256;
    const float* wr1 = wr0 + (size_t)16 * 1024;

    f32x4 a0 = {0.f,0.f,0.f,0.f}, a1 = {0.f,0.f,0.f,0.f};
#pragma unroll 4
    for (int kb = 0; kb < 256; kb += 32) {
        const int k = kb + kq * 8;
        short8 a  = load_cvt_bf16x8(xr + k);
        short8 b0 = load_cvt_bf16x8(wr0 + k);
        short8 b1 = load_cvt_bf16x8(wr1 + k);
        a0 = __builtin_amdgcn_mfma_f32_16x16x32_bf16(a, b0, a0, 0, 0, 0);
        a1 = __builtin_amdgcn_mfma_f32_16x16x32_bf16(a, b1, a1, 0, 0, 0);
    }

    __shared__ float Ps[16][65];
    if (kz == 1) {
#pragma unroll
        for (int r = 0; r < 4; ++r) {
            Ps[kq * 4 + r][wn + l16]      = a0[r];
            Ps[kq * 4 + r][wn + 16 + l16] = a1[r];
        }
    }
    __syncthreads();
    if (kz == 0) {
        float* p0 = Pd + (size_t)(mb * 16) * 1024 + cBase + wn;
#pragma unroll
        for (int r = 0; r < 4; ++r) {
            const int row = kq * 4 + r;
            p0[(size_t)row * 1024 + l16]      = a0[r] + Ps[row][wn + l16];
            p0[(size_t)row * 1024 + 16 + l16] = a1[r] + Ps[row][wn + 16 + l16];
        }
    }
}

// ---------------- K2: fused enc GEMM + broadcast-add stream ------------------
// Grid (16 c-tiles, 64 bt-tiles), 256 threads = 4 waves.
__global__ __launch_bounds__(256) void fused_enc_stream(
    const ushort* __restrict__ Xe_f,  // frag layout (64 mb x 16 kb)
    const ushort* __restrict__ We_f,  // frag layout (64 cb x 16 kb)
    const float* __restrict__ Pd,     // (256, 1024)
    float* __restrict__ out)          // (1024, 64, 1024)
{
    const int tid  = threadIdx.x;
    const int wave = tid >> 6;
    const int lane = tid & 63;
    const int l16  = lane & 15;
    const int kq   = lane >> 4;

    const int kz = wave >> 1;
    const int wn = (wave & 1) * 32;
    const int btBase = blockIdx.y * 16;
    const int cBase  = blockIdx.x * 64;
    const int b      = blockIdx.y >> 4;
    const int cb0    = blockIdx.x * 4 + (wave & 1) * 2;

    __shared__ float encS[2][16][68];
    __shared__ float decS[64][64];

    // Stage decS (R12-proven): 4096 floats = 4 float4 per thread.
#pragma unroll
    for (int p = 0; p < 4; ++p) {
        int s    = tid + p * 256;
        int row  = s >> 4;
        int slot = s & 15;
        float4 v = *(const float4*)&Pd[(size_t)(b * 64 + row) * 1024 + cBase + slot * 4];
        *(float4*)&decS[row][slot * 4] = v;
    }

    // Enc GEMM: 16 x 64 tile, fragment loads, 2-way split-K.
    {
        const short8* xa  = (const short8*)Xe_f + (size_t)(blockIdx.y * 16 + kz * 8) * 64 + lane;
        const short8* wb0 = (const short8*)We_f + (size_t)(cb0       * 16 + kz * 8) * 64 + lane;
        const short8* wb1 = (const short8*)We_f + (size_t)((cb0 + 1) * 16 + kz * 8) * 64 + lane;
        f32x4 a0 = {0.f,0.f,0.f,0.f}, a1 = {0.f,0.f,0.f,0.f};
#pragma unroll
        for (int s = 0; s < 8; ++s) {
            short8 a  = xa [(size_t)s * 64];
            short8 b0 = wb0[(size_t)s * 64];
            short8 b1 = wb1[(size_t)s * 64];
            a0 = __builtin_amdgcn_mfma_f32_16x16x32_bf16(a, b0, a0, 0, 0, 0);
            a1 = __builtin_amdgcn_mfma_f32_16x16x32_bf16(a, b1, a1, 0, 0, 0);
        }
#pragma unroll
        for (int r = 0; r < 4; ++r) {        // D: col=l16, row=kq*4+r
            encS[kz][kq * 4 + r][wn + l16]      = a0[r];
            encS[kz][kq * 4 + r][wn + 16 + l16] = a1[r];
        }
    }

    __syncthreads();

    // Stream: thread (row=tid>>4, slot=tid&15); decS from LDS, cached stores.
    const int row = tid >> 4;
    const int c4  = (tid & 15) * 4;

    const float4 e0 = *(const float4*)&encS[0][row][c4];
    const float4 e1 = *(const float4*)&encS[1][row][c4];
    const v4f e = {e0.x + e1.x, e0.y + e1.y, e0.z + e1.z, e0.w + e1.w};

    float* po = out + (size_t)(btBase + row) * 64 * 1024 + cBase + c4;

#pragma unroll 8
    for (int u = 0; u < 64; ++u) {
        float4 d = *(const float4*)&decS[u][c4];
        v4f r = {e.x + d.x, e.y + d.y, e.z + d.z, e.w + d.w};
        *(v4f*)&po[(size_t)u * 1024] = r;
    }
}

extern "C" void kernel_launch(void* const* d_in, const int* in_sizes, int n_in,
                              void* d_out, int out_size, void* d_ws, size_t ws_size,
                              hipStream_t stream) {
    const float* enc = (const float*)d_in[0];   // (4,256,512)
    const float* dec = (const float*)d_in[1];   // (4,64,512)
    const float* W   = (const float*)d_in[2];   // (1024,1024)
    float* out = (float*)d_out;

    // Workspace: Pd 1 MiB | Xe_f 1 MiB | We_f 1 MiB   (= 3 MiB)
    char* ws = (char*)d_ws;
    float*  Pd   = (float*)(ws);
    ushort* Xe_f = (ushort*)(ws + (1u << 20));
    ushort* We_f = (ushort*)(ws + (2u << 20));

    cvt_and_dec<<<dim3(768), 256, 0, stream>>>(enc, dec, W, Xe_f, We_f, Pd);
    fused_enc_stream<<<dim3(16, 64), 256, 0, stream>>>(Xe_f, We_f, Pd, out);
}